// Round 17
// baseline (204.175 us; speedup 1.0000x reference)
//
#include <hip/hip_runtime.h>
#include <hip/hip_bf16.h>

// GeRN fused, round 17:
//  GeRN_prepEps: weights -> bf16 B-frag layout ONLY (236 blocks; the 6144
//    eps blocks are gone — eps is re-inlined into recur).
//  GeRN_recur<0>: round-15/16 structure (recur ~147us: WI/WG in LDS, 512thr,
//    152KB LDS, 1 blk/CU, pinned head frags) with threefry/erfinv computed
//    inline in P3. Rationale: r7 hoisted eps when recur was VALU-bound
//    (73%); now VALUBusy=47% -> the ~440 VALU inst/step hide under latency
//    stalls, and we save the ~22us eps kernel + 100MB HBM round-trip.

typedef __attribute__((ext_vector_type(8))) short bf16x8;
typedef __attribute__((ext_vector_type(4))) float f32x4;

#define MFMA(A, Bv, C) __builtin_amdgcn_mfma_f32_16x16x32_bf16(A, Bv, C, 0, 0, 0)

// frag-buffer element offsets (unsigned short units), per side
#define FR_WI   0
#define FR_WG   32768
#define FR_WPR  65536
#define FR_WPO  73728
#define FR_WD   81920
#define FR_SIDE 90112   // per side

__device__ __forceinline__ unsigned short f2bf(float f) {
  unsigned u = __float_as_uint(f);
  return (unsigned short)((u + 0x7FFFu + ((u >> 16) & 1u)) >> 16);
}
__device__ __forceinline__ unsigned pk2(float a, float b) {
  return (unsigned)f2bf(a) | ((unsigned)f2bf(b) << 16);
}
__device__ __forceinline__ float sigf(float x) {
  return 1.0f / (1.0f + __expf(-x));
}
__device__ __forceinline__ float tanh_f(float x) {
  return 1.0f - 2.0f / (__expf(2.0f * x) + 1.0f);
}

// --- JAX threefry2x32-20 (partitionable) + uniform + XLA ErfInv32 ---
__device__ __forceinline__ float eps_threefry(unsigned seed, unsigned idx) {
  unsigned x0 = 0u, x1 = idx;
  const unsigned ks0 = 0u, ks1 = seed, ks2 = seed ^ 0x1BD11BDAu;
  x0 += ks0; x1 += ks1;
#define TF_R(r) { x0 += x1; x1 = (x1 << (r)) | (x1 >> (32 - (r))); x1 ^= x0; }
  TF_R(13) TF_R(15) TF_R(26) TF_R(6)  x0 += ks1; x1 += ks2 + 1u;
  TF_R(17) TF_R(29) TF_R(16) TF_R(24) x0 += ks2; x1 += ks0 + 2u;
  TF_R(13) TF_R(15) TF_R(26) TF_R(6)  x0 += ks0; x1 += ks1 + 3u;
  TF_R(17) TF_R(29) TF_R(16) TF_R(24) x0 += ks1; x1 += ks2 + 4u;
  TF_R(13) TF_R(15) TF_R(26) TF_R(6)  x0 += ks2; x1 += ks0 + 5u;
#undef TF_R
  unsigned bits = x0 ^ x1;
  unsigned fb = (bits >> 9) | 0x3F800000u;
  const float lo = -0.99999994f;
  float f = __uint_as_float(fb) - 1.0f;
  float u = fmaxf(lo, f * 2.0f + lo);
  float w = -log1pf(-u * u);
  float p;
  if (w < 5.0f) {
    w -= 2.5f;
    p = 2.81022636e-08f;
    p = fmaf(p, w, 3.43273939e-07f);
    p = fmaf(p, w, -3.5233877e-06f);
    p = fmaf(p, w, -4.39150654e-06f);
    p = fmaf(p, w, 0.00021858087f);
    p = fmaf(p, w, -0.00125372503f);
    p = fmaf(p, w, -0.00417768164f);
    p = fmaf(p, w, 0.246640727f);
    p = fmaf(p, w, 1.50140941f);
  } else {
    w = sqrtf(w) - 3.0f;
    p = -0.000200214257f;
    p = fmaf(p, w, 0.000100950558f);
    p = fmaf(p, w, 0.00134934322f);
    p = fmaf(p, w, -0.00367342844f);
    p = fmaf(p, w, 0.00573950773f);
    p = fmaf(p, w, -0.0076224613f);
    p = fmaf(p, w, 0.00943887047f);
    p = fmaf(p, w, 1.00167406f);
    p = fmaf(p, w, 2.83297682f);
  }
  return 1.41421356f * (p * u);
}

// ============ Kernel 1: prep (weights -> B-frag layout only) ===============
__global__ __launch_bounds__(256) void GeRN_prepEps(
    const float* __restrict__ Wij, const float* __restrict__ Wid,
    const float* __restrict__ Wgj, const float* __restrict__ Wgd,
    const float* __restrict__ Wprj, const float* __restrict__ Wprd,
    const float* __restrict__ Wpoj, const float* __restrict__ Wpod,
    const float* __restrict__ Wdj, const float* __restrict__ Wdd,
    unsigned short* __restrict__ frB, unsigned short* __restrict__ sBs)
{
  const int vb = blockIdx.x * 4 + (threadIdx.x >> 6);
  const int l = threadIdx.x & 63;
  if (vb < 352) {
    const int s = vb / 176;
    int tt = vb % 176;
    const float* W; int ldw, rb, NT, kt, nt; size_t doff;
    if (tt < 64)       { W = s ? Wid : Wij; ldw = 256; NT = 16; kt = tt >> 4; nt = tt & 15;
                         rb = 320 + kt * 32; doff = FR_WI; }
    else if (tt < 128) { tt -= 64; W = s ? Wgd : Wgj; ldw = 256; NT = 16; kt = tt >> 4; nt = tt & 15;
                         rb = (kt < 2) ? 256 + kt * 32 : (s ? 324 : 320) + (kt - 2) * 32; doff = FR_WG; }
    else if (tt < 144) { tt -= 128; W = s ? Wprd : Wprj; ldw = 128; NT = 8; kt = tt >> 3; nt = tt & 7;
                         rb = kt * 32; doff = FR_WPR; }
    else if (tt < 160) { tt -= 144; W = s ? Wpod : Wpoj; ldw = 128; NT = 8; kt = tt >> 3; nt = tt & 7;
                         rb = kt * 32; doff = FR_WPO; }
    else               { tt -= 160; W = s ? Wdd : Wdj; ldw = 64; NT = 4; kt = tt >> 2; nt = tt & 3;
                         rb = (kt < 2) ? kt * 32 : 64 + (kt - 2) * 32; doff = FR_WD; }
    unsigned short* dst = frB + (size_t)s * FR_SIDE + doff
                        + ((size_t)(kt * NT + nt) * 64 + l) * 8;
    const int kk = (l >> 4) * 8;
    const int c = nt * 16 + (l & 15);
    #pragma unroll
    for (int j = 0; j < 8; ++j)
      dst[j] = f2bf(W[(size_t)(rb + kk + j) * ldw + c]);
  } else {
    int bb = vb - 352;        // static tile id 0..591
    int mat, base;
    if (bb < 160)      { mat = 0; base = 0; }
    else if (bb < 320) { mat = 1; base = 160; }
    else if (bb < 448) { mat = 2; base = 320; }
    else               { mat = 3; base = 448; }
    int tt = bb - base;
    int kk = tt >> 4, nt = tt & 15;
    const float* W = mat == 0 ? Wij : mat == 1 ? Wid : mat == 2 ? Wgj : Wgd;
    const int c = nt * 16 + (l & 15);
    const int kl0 = (l >> 4) * 8;
    unsigned short* dst = sBs + ((size_t)bb * 64 + l) * 8;
    if (mat == 3 && kk == 8) {          // qv rows 320..323 + zero pad
      #pragma unroll
      for (int j = 0; j < 8; ++j) {
        int klo = kl0 + j;
        dst[j] = (klo < 4) ? f2bf(W[(size_t)(320 + klo) * 256 + c]) : (unsigned short)0;
      }
    } else {
      int rb = (kk < 8) ? kk * 32 : 256 + (kk - 8) * 32;
      #pragma unroll
      for (int j = 0; j < 8; ++j)
        dst[j] = f2bf(W[(size_t)(rb + kl0 + j) * 256 + c]);
    }
  }
}

// ============ Kernel 2: fused recurrence, WI/WG LDS + inline eps ===========
// 512 thr = 8 waves; wave w: rh = w>>2 (row-half), ws = w&3 (col-slice).
// 32 rows/block; block = (side, 32-row tile); grid = 2*(B/32).
// fr bufs per rh: 0,1 hi dbuf; 2 hg; 3 z; 4,5 u dbuf.
#define WR_FR(buf, row, c, v) \
  fr[rh][buf][(c) >> 5][((row) & 15) + (((c) >> 3) & 3) * 16][(c) & 7] = f2bf(v)
#define LD_FR(buf, kt) (*(const bf16x8*)&fr[rh][buf][kt][l][0])
#define LD_B(off, kt, nt, NT) \
  (*(const bf16x8*)(FB + (off) + (((kt) * (NT) + (nt)) * 64 + l) * 8))
#define LD_S(idx) (*(const bf16x8*)&sBs[((size_t)(idx) * 64 + l) * 8])
#define LD_WI(kt, nt) (*(const bf16x8*)&wiL[(((kt) * 16 + (nt)) * 64 + l) * 8])
#define LD_WG(kt, nt) (*(const bf16x8*)&wgL[(((kt) * 16 + (nt)) * 64 + l) * 8])
#define LD_A(kt) (*(const bf16x8*)&AsBuf[(((size_t)rh * 11 + (kt)) * 64 + l) * 8])

template<int USE_EPS>
__global__ __launch_bounds__(512, 2) void GeRN_recur(
    const unsigned short* __restrict__ frB,
    const unsigned short* __restrict__ sBs,
    const float* __restrict__ cnd, const float* __restrict__ qjg,
    const float* __restrict__ qdg, const float* __restrict__ qvg,
    const float* __restrict__ bij, const float* __restrict__ bid,
    const float* __restrict__ bgj, const float* __restrict__ bgd,
    const float* __restrict__ bprj, const float* __restrict__ bprd,
    const float* __restrict__ bpoj, const float* __restrict__ bpod,
    const float* __restrict__ bdj,  const float* __restrict__ bdd,
    const float* __restrict__ hi_j0, const float* __restrict__ ci_j0,
    const float* __restrict__ hi_d0, const float* __restrict__ ci_d0,
    const float* __restrict__ hg_j0, const float* __restrict__ cg_j0,
    const float* __restrict__ hg_d0, const float* __restrict__ cg_d0,
    const float* __restrict__ ug_j0, const float* __restrict__ ug_d0,
    const float* __restrict__ eps_buf, unsigned ndBN,
    float* __restrict__ out, int B, int nd)
{
  alignas(16) __shared__ unsigned short fr[2][6][2][64][8];   // 24 KB
  alignas(16) __shared__ unsigned short wiL[32768];           // 64 KB (WI)
  alignas(16) __shared__ unsigned short wgL[32768];           // 64 KB (WG; aliases AsBuf in prologue)
  unsigned short* AsBuf = wgL;   // 2*11 tiles = 22 KB, used before WG staged

  const int tid = threadIdx.x;
  const int l   = tid & 63;
  const int w   = tid >> 6;
  const int rh  = w >> 2;          // row-half (wave-uniform)
  const int ws  = w & 3;           // col-slice (wave-uniform)
  const int s   = blockIdx.x & 1;  // 0=j, 1=d
  const int rbk = blockIdx.x >> 1;
  const int r0  = (l >> 4) * 4;
  const int col = ws * 16 + (l & 15);
  const int bbase = rbk * 32 + rh * 16;     // this wave's 16-row tile base
  const int bblk  = rbk * 32;               // block's 32-row base
  const size_t BN = (size_t)B * 64;

  const float* hi0 = s ? hi_d0 : hi_j0;  const float* ci0 = s ? ci_d0 : ci_j0;
  const float* hg0 = s ? hg_d0 : hg_j0;  const float* cg0 = s ? cg_d0 : cg_j0;
  const float* ug0 = s ? ug_d0 : ug_j0;
  const float* BPR = s ? bprd : bprj;
  const float* BPO = s ? bpod : bpoj;
  const float* BD  = s ? bdd  : bdj;
  const float* BI  = s ? bid  : bij;
  const float* BG  = s ? bgd  : bgj;
  const float* qq  = s ? qdg  : qjg;
  const unsigned short* FB = frB + (size_t)s * FR_SIDE;

  // ---- loop-invariant head/delta B-frags -> registers, pinned ----
  bf16x8 wpr[2][2], wpo[2][2], wd[4];
  #pragma unroll
  for (int kt = 0; kt < 2; ++kt) {
    wpr[kt][0] = LD_B(FR_WPR, kt, ws, 8);
    wpr[kt][1] = LD_B(FR_WPR, kt, ws + 4, 8);
    wpo[kt][0] = LD_B(FR_WPO, kt, ws, 8);
    wpo[kt][1] = LD_B(FR_WPO, kt, ws + 4, 8);
  }
  #pragma unroll
  for (int kt = 0; kt < 4; ++kt) wd[kt] = LD_B(FR_WD, kt, ws, 4);
  #pragma unroll
  for (int kt = 0; kt < 2; ++kt)
    asm volatile("" : "+v"(wpr[kt][0]), "+v"(wpr[kt][1]),
                      "+v"(wpo[kt][0]), "+v"(wpo[kt][1]));
  #pragma unroll
  for (int kt = 0; kt < 4; ++kt) asm volatile("" : "+v"(wd[kt]));

  // ---- stage static A-frags into AsBuf (aliases wgL): 32 rows x 11 kt ----
  for (int i = tid; i < 32 * 44; i += 512) {
    int r = i / 44, kc = i % 44;
    int rhh = r >> 4, rr = r & 15;
    float v[8];
    if (kc < 32) {
      const float4* p = (const float4*)&cnd[(size_t)(bblk + r) * 256 + kc * 8];
      float4 x0 = p[0], x1 = p[1];
      v[0] = x0.x; v[1] = x0.y; v[2] = x0.z; v[3] = x0.w;
      v[4] = x1.x; v[5] = x1.y; v[6] = x1.z; v[7] = x1.w;
    } else if (kc < 40) {
      const float4* p = (const float4*)&qq[(size_t)(bblk + r) * 64 + (kc - 32) * 8];
      float4 x0 = p[0], x1 = p[1];
      v[0] = x0.x; v[1] = x0.y; v[2] = x0.z; v[3] = x0.w;
      v[4] = x1.x; v[5] = x1.y; v[6] = x1.z; v[7] = x1.w;
    } else if (kc == 40 && s) {
      #pragma unroll
      for (int j = 0; j < 8; ++j) v[j] = (j < 4) ? qvg[(size_t)(bblk + r) * 4 + j] : 0.0f;
    } else {
      #pragma unroll
      for (int j = 0; j < 8; ++j) v[j] = 0.0f;
    }
    int kt = kc >> 2;
    int lane = rr + (kc & 3) * 16;
    uint4 wq;
    wq.x = pk2(v[0], v[1]); wq.y = pk2(v[2], v[3]);
    wq.z = pk2(v[4], v[5]); wq.w = pk2(v[6], v[7]);
    *(uint4*)&AsBuf[(((size_t)rhh * 11 + kt) * 64 + lane) * 8] = wq;
  }
  __syncthreads();

  // ---- static pre-activations -> register accumulators (sBs from L2) ----
  f32x4 preI[4], preG[4];
  {
    const int ktB_I = s ? 160 : 0;
    const int ktB_G = s ? 448 : 320;
    const int ktN_G = s ? 9 : 8;
    #pragma unroll
    for (int g = 0; g < 4; ++g) {
      float bi = BI[g * 64 + col];
      float bg = BG[g * 64 + col];
      f32x4 vi = {bi, bi, bi, bi};
      f32x4 vg = {bg, bg, bg, bg};
      preI[g] = vi; preG[g] = vg;
    }
    #pragma unroll
    for (int kk = 0; kk < 10; ++kk) {
      bf16x8 a = LD_A(kk);
      #pragma unroll
      for (int g = 0; g < 4; ++g)
        preI[g] = MFMA(a, LD_S(ktB_I + kk * 16 + g * 4 + ws), preI[g]);
    }
    for (int kk = 0; kk < ktN_G; ++kk) {
      int ktA = (kk < 8) ? kk : 10;
      bf16x8 a = LD_A(ktA);
      #pragma unroll
      for (int g = 0; g < 4; ++g)
        preG[g] = MFMA(a, LD_S(ktB_G + kk * 16 + g * 4 + ws), preG[g]);
    }
  }

  // ---- states ----
  float hi_[4], ci_[4], hg_[4], cg_[4], u_[4];
  #pragma unroll
  for (int r = 0; r < 4; ++r) {
    size_t gi = (size_t)(bbase + r0 + r) * 64 + col;
    hi_[r] = hi0[gi]; ci_[r] = ci0[gi];
    hg_[r] = hg0[gi]; cg_[r] = cg0[gi];
    u_[r]  = ug0[gi];
  }
  const float bprm = BPR[col], bprv = BPR[64 + col];
  const float bpom = BPO[col], bpov = BPO[64 + col];
  const float bd   = BD[col];

  #pragma unroll
  for (int r = 0; r < 4; ++r) {
    WR_FR(0, r0 + r, col, hi_[r]);   // hi -> H0
    WR_FR(2, r0 + r, col, hg_[r]);
    WR_FR(4, r0 + r, col, u_[r]);    // u -> U0
  }
  __syncthreads();   // As reads done + fr visible; wgL may now be overwritten

  // ---- stage WI/WG B-frags into LDS (64 KB each from L2) ----
  {
    const uint4* srcI = (const uint4*)(FB + FR_WI);
    uint4* dI = (uint4*)wiL;
    for (int i = tid; i < 4096; i += 512) dI[i] = srcI[i];
    const uint4* srcG = (const uint4*)(FB + FR_WG);
    uint4* dG = (uint4*)wgL;
    for (int i = tid; i < 4096; i += 512) dG[i] = srcG[i];
  }
  __syncthreads();

  const float zo = s ? 0.2f : 0.3f, zo1 = 1.0f - zo;

  // ---- hoisted output pointers & eps stream ----
  const unsigned gi0 = (unsigned)((bbase + r0) * 64 + col);
  float* o_prm = out + (size_t)(2 + (2 * s) * nd) * BN + gi0;
  float* o_prv = out + (size_t)(2 + (2 * s + 1) * nd) * BN + gi0;
  float* o_pom = out + (size_t)(2 + (4 + 2 * s) * nd) * BN + gi0;
  float* o_pov = out + (size_t)(2 + (5 + 2 * s) * nd) * BN + gi0;
  unsigned e0 = gi0;
  const unsigned BNu = (unsigned)BN;
  const unsigned eseed = 1u + (unsigned)s;
  const float* ep = USE_EPS ? (eps_buf + (size_t)s * ndBN + gi0) : (const float*)0;

  for (int t = 0; t < nd; ++t) {
    const int cb = t & 1;
    // ---- eps prefetch (used in P3) ----
    float epre[4];
    if (USE_EPS) {
      #pragma unroll
      for (int r = 0; r < 4; ++r) epre[r] = ep[r * 64];
    }
    // ---- P1: A-frags of hg_old, hi_old ----
    bf16x8 a_hg0 = LD_FR(2, 0), a_hg1 = LD_FR(2, 1);
    bf16x8 a_hi0 = LD_FR(cb, 0), a_hi1 = LD_FR(cb, 1);

    // ---- P2: prior head (regs) + inference LSTM (LDS weights) ----
    {
      f32x4 am = {bprm, bprm, bprm, bprm};
      f32x4 av = {bprv, bprv, bprv, bprv};
      am = MFMA(a_hg0, wpr[0][0], am);
      am = MFMA(a_hg1, wpr[1][0], am);
      av = MFMA(a_hg0, wpr[0][1], av);
      av = MFMA(a_hg1, wpr[1][1], av);
      #pragma unroll
      for (int r = 0; r < 4; ++r) {
        o_prm[r * 64] = am[r];
        o_prv[r * 64] = av[r];
      }
    }
    {
      f32x4 acc[4];
      #pragma unroll
      for (int g = 0; g < 4; ++g) acc[g] = preI[g];
      #pragma unroll
      for (int g = 0; g < 4; ++g) {
        acc[g] = MFMA(a_hg0, LD_WI(0, g * 4 + ws), acc[g]);
        acc[g] = MFMA(a_hg1, LD_WI(1, g * 4 + ws), acc[g]);
        acc[g] = MFMA(a_hi0, LD_WI(2, g * 4 + ws), acc[g]);
        acc[g] = MFMA(a_hi1, LD_WI(3, g * 4 + ws), acc[g]);
      }
      #pragma unroll
      for (int r = 0; r < 4; ++r) {
        float ig = sigf(acc[0][r]), fg = sigf(acc[1][r]);
        float gg = tanh_f(acc[2][r]), og = sigf(acc[3][r]);
        float cn = fmaf(fg, ci_[r], ig * gg);
        float hn = og * tanh_f(cn);
        hi_[r] = fmaf(zo, hi_[r], zo1 * hn);
        ci_[r] = fmaf(zo, ci_[r], zo1 * cn);
        WR_FR(cb ^ 1, r0 + r, col, hi_[r]);   // new hi -> other buffer
      }
    }
    __syncthreads();                                 // B2

    // ---- P3: posterior head (regs) + z sample (inline threefry) ----
    {
      bf16x8 a0 = LD_FR(cb ^ 1, 0), a1 = LD_FR(cb ^ 1, 1);
      f32x4 am = {bpom, bpom, bpom, bpom};
      f32x4 av = {bpov, bpov, bpov, bpov};
      am = MFMA(a0, wpo[0][0], am);
      am = MFMA(a1, wpo[1][0], am);
      av = MFMA(a0, wpo[0][1], av);
      av = MFMA(a1, wpo[1][1], av);
      #pragma unroll
      for (int r = 0; r < 4; ++r) {
        o_pom[r * 64] = am[r];
        o_pov[r * 64] = av[r];
        float e = USE_EPS ? epre[r] : eps_threefry(eseed, e0 + r * 64);
        float z = fmaf(__expf(0.5f * av[r]), e, am[r]);
        WR_FR(3, r0 + r, col, z);
      }
    }
    __syncthreads();                                 // B3

    // ---- P4: generator LSTM (LDS weights; x1 = z, x2 = hg_old) ----
    {
      bf16x8 az0 = LD_FR(3, 0), az1 = LD_FR(3, 1);
      f32x4 acc[4];
      #pragma unroll
      for (int g = 0; g < 4; ++g) acc[g] = preG[g];
      #pragma unroll
      for (int g = 0; g < 4; ++g) {
        acc[g] = MFMA(az0,   LD_WG(0, g * 4 + ws), acc[g]);
        acc[g] = MFMA(az1,   LD_WG(1, g * 4 + ws), acc[g]);
        acc[g] = MFMA(a_hg0, LD_WG(2, g * 4 + ws), acc[g]);
        acc[g] = MFMA(a_hg1, LD_WG(3, g * 4 + ws), acc[g]);
      }
      #pragma unroll
      for (int r = 0; r < 4; ++r) {
        float ig = sigf(acc[0][r]), fg = sigf(acc[1][r]);
        float gg = tanh_f(acc[2][r]), og = sigf(acc[3][r]);
        float cn = fmaf(fg, cg_[r], ig * gg);
        float hn = og * tanh_f(cn);
        hg_[r] = fmaf(zo, hg_[r], zo1 * hn);
        cg_[r] = fmaf(zo, cg_[r], zo1 * cn);
        WR_FR(2, r0 + r, col, hg_[r]);
      }
    }
    __syncthreads();                                 // B4

    // ---- P5: canvas delta (WD in regs) ----
    {
      bf16x8 au0 = LD_FR(4 + cb, 0), au1 = LD_FR(4 + cb, 1);
      bf16x8 ah0 = LD_FR(2, 0), ah1 = LD_FR(2, 1);
      f32x4 acc = {bd, bd, bd, bd};
      acc = MFMA(au0, wd[0], acc);
      acc = MFMA(au1, wd[1], acc);
      acc = MFMA(ah0, wd[2], acc);
      acc = MFMA(ah1, wd[3], acc);
      #pragma unroll
      for (int r = 0; r < 4; ++r) {
        float a = acc[r];
        float d = a > 0.0f ? a : 0.01f * a;
        u_[r] += d;
        WR_FR(4 + (cb ^ 1), r0 + r, col, u_[r]);   // new u -> other buffer
      }
    }
    __syncthreads();                                 // B6

    o_prm += BN; o_prv += BN; o_pom += BN; o_pov += BN;
    e0 += BNu;
    if (USE_EPS) ep += BN;
  }

  // ---- final canvases ----
  #pragma unroll
  for (int r = 0; r < 4; ++r) {
    size_t gi = (size_t)(bbase + r0 + r) * 64 + col;
    out[(size_t)s * BN + gi] = u_[r];
  }
}

extern "C" void kernel_launch(void* const* d_in, const int* in_sizes, int n_in,
                              void* d_out, int out_size, void* d_ws, size_t ws_size,
                              hipStream_t stream)
{
  const float* cnd = (const float*)d_in[1];
  const float* qj  = (const float*)d_in[2];
  const float* qd  = (const float*)d_in[3];
  const float* qv  = (const float*)d_in[4];
  const float* hi_j0 = (const float*)d_in[5];
  const float* ci_j0 = (const float*)d_in[6];
  const float* hi_d0 = (const float*)d_in[8];
  const float* ci_d0 = (const float*)d_in[9];
  const float* hg_j0 = (const float*)d_in[11];
  const float* cg_j0 = (const float*)d_in[12];
  const float* hg_d0 = (const float*)d_in[14];
  const float* cg_d0 = (const float*)d_in[15];
  const float* ug_j0 = (const float*)d_in[17];
  const float* ug_d0 = (const float*)d_in[18];
  const float* Wij = (const float*)d_in[19]; const float* bij = (const float*)d_in[20];
  const float* Wid = (const float*)d_in[21]; const float* bid = (const float*)d_in[22];
  const float* Wgj = (const float*)d_in[23]; const float* bgj = (const float*)d_in[24];
  const float* Wgd = (const float*)d_in[25]; const float* bgd = (const float*)d_in[26];
  const float* Wpoj = (const float*)d_in[27]; const float* bpoj = (const float*)d_in[28];
  const float* Wpod = (const float*)d_in[29]; const float* bpod = (const float*)d_in[30];
  const float* Wprj = (const float*)d_in[31]; const float* bprj = (const float*)d_in[32];
  const float* Wprd = (const float*)d_in[33]; const float* bprd = (const float*)d_in[34];
  const float* Wdj = (const float*)d_in[35]; const float* bdj = (const float*)d_in[36];
  const float* Wdd = (const float*)d_in[37]; const float* bdd = (const float*)d_in[38];

  const int B = in_sizes[1] / 256;                 // cnd_repr is [B,256]
  const int slots = out_size / (B * 64);           // 2 + 8*ndraw
  const int nd = (slots - 2) / 8;

  // ws layout: frB (2*FR_SIDE u16) | sBs (592*512 u16)
  unsigned short* frB = (unsigned short*)d_ws;
  unsigned short* sBs = frB + 2 * FR_SIDE;
  const unsigned ndBN = (unsigned)((size_t)nd * B * 64);
  float* out = (float*)d_out;

  GeRN_prepEps<<<236, 256, 0, stream>>>(
      Wij, Wid, Wgj, Wgd, Wprj, Wprd, Wpoj, Wpod, Wdj, Wdd, frB, sBs);
  GeRN_recur<0><<<2 * (B / 32), 512, 0, stream>>>(
      frB, sBs, cnd, qj, qd, qv, bij, bid, bgj, bgd,
      bprj, bprd, bpoj, bpod, bdj, bdd,
      hi_j0, ci_j0, hi_d0, ci_d0, hg_j0, cg_j0, hg_d0, cg_d0, ug_j0, ug_d0,
      (const float*)0, ndBN, out, B, nd);
}

// Round 18
// 189.619 us; speedup vs baseline: 1.0768x; 1.0768x over previous
//
#include <hip/hip_runtime.h>
#include <hip/hip_bf16.h>

// GeRN fused, round 18:
//  REVERT of r17 (inline eps made recur VALU-bound: 148->228us; at 2
//  waves/SIMD lockstep the serial threefry chain adds straight to the
//  critical path). Back to r15/16 best-known (191.2us): eps precomputed in
//  prepEps, WI/WG in LDS, pinned head frags, lb(512,2).
//  + ONE audited change: barrier B6 (after P5) removed. P5 writes only the
//  u double-buffer whose next reader (P5 of t+1) is separated by B2/B3/B4;
//  next-step P1/P2 touch disjoint buffers. 3 barriers/step is the floor
//  for this phase structure (P2->P3 hi, P3->P4 z, P4->P5 hg).

typedef __attribute__((ext_vector_type(8))) short bf16x8;
typedef __attribute__((ext_vector_type(4))) float f32x4;

#define MFMA(A, Bv, C) __builtin_amdgcn_mfma_f32_16x16x32_bf16(A, Bv, C, 0, 0, 0)

// frag-buffer element offsets (unsigned short units), per side
#define FR_WI   0
#define FR_WG   32768
#define FR_WPR  65536
#define FR_WPO  73728
#define FR_WD   81920
#define FR_SIDE 90112   // per side

__device__ __forceinline__ unsigned short f2bf(float f) {
  unsigned u = __float_as_uint(f);
  return (unsigned short)((u + 0x7FFFu + ((u >> 16) & 1u)) >> 16);
}
__device__ __forceinline__ unsigned pk2(float a, float b) {
  return (unsigned)f2bf(a) | ((unsigned)f2bf(b) << 16);
}
__device__ __forceinline__ float sigf(float x) {
  return 1.0f / (1.0f + __expf(-x));
}
__device__ __forceinline__ float tanh_f(float x) {
  return 1.0f - 2.0f / (__expf(2.0f * x) + 1.0f);
}

// --- JAX threefry2x32-20 (partitionable) + uniform + XLA ErfInv32 ---
__device__ __forceinline__ float eps_threefry(unsigned seed, unsigned idx) {
  unsigned x0 = 0u, x1 = idx;
  const unsigned ks0 = 0u, ks1 = seed, ks2 = seed ^ 0x1BD11BDAu;
  x0 += ks0; x1 += ks1;
#define TF_R(r) { x0 += x1; x1 = (x1 << (r)) | (x1 >> (32 - (r))); x1 ^= x0; }
  TF_R(13) TF_R(15) TF_R(26) TF_R(6)  x0 += ks1; x1 += ks2 + 1u;
  TF_R(17) TF_R(29) TF_R(16) TF_R(24) x0 += ks2; x1 += ks0 + 2u;
  TF_R(13) TF_R(15) TF_R(26) TF_R(6)  x0 += ks0; x1 += ks1 + 3u;
  TF_R(17) TF_R(29) TF_R(16) TF_R(24) x0 += ks1; x1 += ks2 + 4u;
  TF_R(13) TF_R(15) TF_R(26) TF_R(6)  x0 += ks2; x1 += ks0 + 5u;
#undef TF_R
  unsigned bits = x0 ^ x1;
  unsigned fb = (bits >> 9) | 0x3F800000u;
  const float lo = -0.99999994f;
  float f = __uint_as_float(fb) - 1.0f;
  float u = fmaxf(lo, f * 2.0f + lo);
  float w = -log1pf(-u * u);
  float p;
  if (w < 5.0f) {
    w -= 2.5f;
    p = 2.81022636e-08f;
    p = fmaf(p, w, 3.43273939e-07f);
    p = fmaf(p, w, -3.5233877e-06f);
    p = fmaf(p, w, -4.39150654e-06f);
    p = fmaf(p, w, 0.00021858087f);
    p = fmaf(p, w, -0.00125372503f);
    p = fmaf(p, w, -0.00417768164f);
    p = fmaf(p, w, 0.246640727f);
    p = fmaf(p, w, 1.50140941f);
  } else {
    w = sqrtf(w) - 3.0f;
    p = -0.000200214257f;
    p = fmaf(p, w, 0.000100950558f);
    p = fmaf(p, w, 0.00134934322f);
    p = fmaf(p, w, -0.00367342844f);
    p = fmaf(p, w, 0.00573950773f);
    p = fmaf(p, w, -0.0076224613f);
    p = fmaf(p, w, 0.00943887047f);
    p = fmaf(p, w, 1.00167406f);
    p = fmaf(p, w, 2.83297682f);
  }
  return 1.41421356f * (p * u);
}

// ============ Kernel 1: prep (weights->frags) + eps precompute =============
__global__ __launch_bounds__(256) void GeRN_prepEps(
    const float* __restrict__ Wij, const float* __restrict__ Wid,
    const float* __restrict__ Wgj, const float* __restrict__ Wgd,
    const float* __restrict__ Wprj, const float* __restrict__ Wprd,
    const float* __restrict__ Wpoj, const float* __restrict__ Wpod,
    const float* __restrict__ Wdj, const float* __restrict__ Wdd,
    unsigned short* __restrict__ frB, unsigned short* __restrict__ sBs,
    float* __restrict__ ebuf, unsigned ndBN)
{
  if (blockIdx.x < 236) {
    const int vb = blockIdx.x * 4 + (threadIdx.x >> 6);
    const int l = threadIdx.x & 63;
    if (vb < 352) {
      const int s = vb / 176;
      int tt = vb % 176;
      const float* W; int ldw, rb, NT, kt, nt; size_t doff;
      if (tt < 64)       { W = s ? Wid : Wij; ldw = 256; NT = 16; kt = tt >> 4; nt = tt & 15;
                           rb = 320 + kt * 32; doff = FR_WI; }
      else if (tt < 128) { tt -= 64; W = s ? Wgd : Wgj; ldw = 256; NT = 16; kt = tt >> 4; nt = tt & 15;
                           rb = (kt < 2) ? 256 + kt * 32 : (s ? 324 : 320) + (kt - 2) * 32; doff = FR_WG; }
      else if (tt < 144) { tt -= 128; W = s ? Wprd : Wprj; ldw = 128; NT = 8; kt = tt >> 3; nt = tt & 7;
                           rb = kt * 32; doff = FR_WPR; }
      else if (tt < 160) { tt -= 144; W = s ? Wpod : Wpoj; ldw = 128; NT = 8; kt = tt >> 3; nt = tt & 7;
                           rb = kt * 32; doff = FR_WPO; }
      else               { tt -= 160; W = s ? Wdd : Wdj; ldw = 64; NT = 4; kt = tt >> 2; nt = tt & 3;
                           rb = (kt < 2) ? kt * 32 : 64 + (kt - 2) * 32; doff = FR_WD; }
      unsigned short* dst = frB + (size_t)s * FR_SIDE + doff
                          + ((size_t)(kt * NT + nt) * 64 + l) * 8;
      const int kk = (l >> 4) * 8;
      const int c = nt * 16 + (l & 15);
      #pragma unroll
      for (int j = 0; j < 8; ++j)
        dst[j] = f2bf(W[(size_t)(rb + kk + j) * ldw + c]);
    } else {
      int bb = vb - 352;        // static tile id 0..591
      int mat, base;
      if (bb < 160)      { mat = 0; base = 0; }
      else if (bb < 320) { mat = 1; base = 160; }
      else if (bb < 448) { mat = 2; base = 320; }
      else               { mat = 3; base = 448; }
      int tt = bb - base;
      int kk = tt >> 4, nt = tt & 15;
      const float* W = mat == 0 ? Wij : mat == 1 ? Wid : mat == 2 ? Wgj : Wgd;
      const int c = nt * 16 + (l & 15);
      const int kl0 = (l >> 4) * 8;
      unsigned short* dst = sBs + ((size_t)bb * 64 + l) * 8;
      if (mat == 3 && kk == 8) {          // qv rows 320..323 + zero pad
        #pragma unroll
        for (int j = 0; j < 8; ++j) {
          int klo = kl0 + j;
          dst[j] = (klo < 4) ? f2bf(W[(size_t)(320 + klo) * 256 + c]) : (unsigned short)0;
        }
      } else {
        int rb = (kk < 8) ? kk * 32 : 256 + (kk - 8) * 32;
        #pragma unroll
        for (int j = 0; j < 8; ++j)
          dst[j] = f2bf(W[(size_t)(rb + kl0 + j) * 256 + c]);
      }
    }
  } else {
    unsigned j0 = ((blockIdx.x - 236) * 256u + threadIdx.x) * 8u;
    const unsigned total = 2u * ndBN;
    if (j0 >= total) return;
    const unsigned s = (j0 >= ndBN) ? 1u : 0u;
    const unsigned i0 = j0 - s * ndBN;
    const unsigned seed = 1u + s;
    float v[8];
    #pragma unroll
    for (int k = 0; k < 8; ++k) v[k] = eps_threefry(seed, i0 + (unsigned)k);
    float4 a = {v[0], v[1], v[2], v[3]};
    float4 b = {v[4], v[5], v[6], v[7]};
    *(float4*)(ebuf + j0) = a;
    *(float4*)(ebuf + j0 + 4) = b;
  }
}

// ============ Kernel 2: fused recurrence, WI/WG LDS, 3 barriers/step =======
// 512 thr = 8 waves; wave w: rh = w>>2 (row-half), ws = w&3 (col-slice).
// 32 rows/block; block = (side, 32-row tile); grid = 2*(B/32).
// fr bufs per rh: 0,1 hi dbuf; 2 hg; 3 z; 4,5 u dbuf.
#define WR_FR(buf, row, c, v) \
  fr[rh][buf][(c) >> 5][((row) & 15) + (((c) >> 3) & 3) * 16][(c) & 7] = f2bf(v)
#define LD_FR(buf, kt) (*(const bf16x8*)&fr[rh][buf][kt][l][0])
#define LD_B(off, kt, nt, NT) \
  (*(const bf16x8*)(FB + (off) + (((kt) * (NT) + (nt)) * 64 + l) * 8))
#define LD_S(idx) (*(const bf16x8*)&sBs[((size_t)(idx) * 64 + l) * 8])
#define LD_WI(kt, nt) (*(const bf16x8*)&wiL[(((kt) * 16 + (nt)) * 64 + l) * 8])
#define LD_WG(kt, nt) (*(const bf16x8*)&wgL[(((kt) * 16 + (nt)) * 64 + l) * 8])
#define LD_A(kt) (*(const bf16x8*)&AsBuf[(((size_t)rh * 11 + (kt)) * 64 + l) * 8])

template<int USE_EPS>
__global__ __launch_bounds__(512, 2) void GeRN_recur(
    const unsigned short* __restrict__ frB,
    const unsigned short* __restrict__ sBs,
    const float* __restrict__ cnd, const float* __restrict__ qjg,
    const float* __restrict__ qdg, const float* __restrict__ qvg,
    const float* __restrict__ bij, const float* __restrict__ bid,
    const float* __restrict__ bgj, const float* __restrict__ bgd,
    const float* __restrict__ bprj, const float* __restrict__ bprd,
    const float* __restrict__ bpoj, const float* __restrict__ bpod,
    const float* __restrict__ bdj,  const float* __restrict__ bdd,
    const float* __restrict__ hi_j0, const float* __restrict__ ci_j0,
    const float* __restrict__ hi_d0, const float* __restrict__ ci_d0,
    const float* __restrict__ hg_j0, const float* __restrict__ cg_j0,
    const float* __restrict__ hg_d0, const float* __restrict__ cg_d0,
    const float* __restrict__ ug_j0, const float* __restrict__ ug_d0,
    const float* __restrict__ eps_buf, unsigned ndBN,
    float* __restrict__ out, int B, int nd)
{
  alignas(16) __shared__ unsigned short fr[2][6][2][64][8];   // 24 KB
  alignas(16) __shared__ unsigned short wiL[32768];           // 64 KB (WI)
  alignas(16) __shared__ unsigned short wgL[32768];           // 64 KB (WG; aliases AsBuf in prologue)
  unsigned short* AsBuf = wgL;   // 2*11 tiles = 22 KB, used before WG staged

  const int tid = threadIdx.x;
  const int l   = tid & 63;
  const int w   = tid >> 6;
  const int rh  = w >> 2;          // row-half (wave-uniform)
  const int ws  = w & 3;           // col-slice (wave-uniform)
  const int s   = blockIdx.x & 1;  // 0=j, 1=d
  const int rbk = blockIdx.x >> 1;
  const int r0  = (l >> 4) * 4;
  const int col = ws * 16 + (l & 15);
  const int bbase = rbk * 32 + rh * 16;     // this wave's 16-row tile base
  const int bblk  = rbk * 32;               // block's 32-row base
  const size_t BN = (size_t)B * 64;

  const float* hi0 = s ? hi_d0 : hi_j0;  const float* ci0 = s ? ci_d0 : ci_j0;
  const float* hg0 = s ? hg_d0 : hg_j0;  const float* cg0 = s ? cg_d0 : cg_j0;
  const float* ug0 = s ? ug_d0 : ug_j0;
  const float* BPR = s ? bprd : bprj;
  const float* BPO = s ? bpod : bpoj;
  const float* BD  = s ? bdd  : bdj;
  const float* BI  = s ? bid  : bij;
  const float* BG  = s ? bgd  : bgj;
  const float* qq  = s ? qdg  : qjg;
  const unsigned short* FB = frB + (size_t)s * FR_SIDE;

  // ---- loop-invariant head/delta B-frags -> registers, pinned ----
  bf16x8 wpr[2][2], wpo[2][2], wd[4];
  #pragma unroll
  for (int kt = 0; kt < 2; ++kt) {
    wpr[kt][0] = LD_B(FR_WPR, kt, ws, 8);
    wpr[kt][1] = LD_B(FR_WPR, kt, ws + 4, 8);
    wpo[kt][0] = LD_B(FR_WPO, kt, ws, 8);
    wpo[kt][1] = LD_B(FR_WPO, kt, ws + 4, 8);
  }
  #pragma unroll
  for (int kt = 0; kt < 4; ++kt) wd[kt] = LD_B(FR_WD, kt, ws, 4);
  #pragma unroll
  for (int kt = 0; kt < 2; ++kt)
    asm volatile("" : "+v"(wpr[kt][0]), "+v"(wpr[kt][1]),
                      "+v"(wpo[kt][0]), "+v"(wpo[kt][1]));
  #pragma unroll
  for (int kt = 0; kt < 4; ++kt) asm volatile("" : "+v"(wd[kt]));

  // ---- stage static A-frags into AsBuf (aliases wgL): 32 rows x 11 kt ----
  for (int i = tid; i < 32 * 44; i += 512) {
    int r = i / 44, kc = i % 44;
    int rhh = r >> 4, rr = r & 15;
    float v[8];
    if (kc < 32) {
      const float4* p = (const float4*)&cnd[(size_t)(bblk + r) * 256 + kc * 8];
      float4 x0 = p[0], x1 = p[1];
      v[0] = x0.x; v[1] = x0.y; v[2] = x0.z; v[3] = x0.w;
      v[4] = x1.x; v[5] = x1.y; v[6] = x1.z; v[7] = x1.w;
    } else if (kc < 40) {
      const float4* p = (const float4*)&qq[(size_t)(bblk + r) * 64 + (kc - 32) * 8];
      float4 x0 = p[0], x1 = p[1];
      v[0] = x0.x; v[1] = x0.y; v[2] = x0.z; v[3] = x0.w;
      v[4] = x1.x; v[5] = x1.y; v[6] = x1.z; v[7] = x1.w;
    } else if (kc == 40 && s) {
      #pragma unroll
      for (int j = 0; j < 8; ++j) v[j] = (j < 4) ? qvg[(size_t)(bblk + r) * 4 + j] : 0.0f;
    } else {
      #pragma unroll
      for (int j = 0; j < 8; ++j) v[j] = 0.0f;
    }
    int kt = kc >> 2;
    int lane = rr + (kc & 3) * 16;
    uint4 wq;
    wq.x = pk2(v[0], v[1]); wq.y = pk2(v[2], v[3]);
    wq.z = pk2(v[4], v[5]); wq.w = pk2(v[6], v[7]);
    *(uint4*)&AsBuf[(((size_t)rhh * 11 + kt) * 64 + lane) * 8] = wq;
  }
  __syncthreads();

  // ---- static pre-activations -> register accumulators (sBs from L2) ----
  f32x4 preI[4], preG[4];
  {
    const int ktB_I = s ? 160 : 0;
    const int ktB_G = s ? 448 : 320;
    const int ktN_G = s ? 9 : 8;
    #pragma unroll
    for (int g = 0; g < 4; ++g) {
      float bi = BI[g * 64 + col];
      float bg = BG[g * 64 + col];
      f32x4 vi = {bi, bi, bi, bi};
      f32x4 vg = {bg, bg, bg, bg};
      preI[g] = vi; preG[g] = vg;
    }
    #pragma unroll
    for (int kk = 0; kk < 10; ++kk) {
      bf16x8 a = LD_A(kk);
      #pragma unroll
      for (int g = 0; g < 4; ++g)
        preI[g] = MFMA(a, LD_S(ktB_I + kk * 16 + g * 4 + ws), preI[g]);
    }
    for (int kk = 0; kk < ktN_G; ++kk) {
      int ktA = (kk < 8) ? kk : 10;
      bf16x8 a = LD_A(ktA);
      #pragma unroll
      for (int g = 0; g < 4; ++g)
        preG[g] = MFMA(a, LD_S(ktB_G + kk * 16 + g * 4 + ws), preG[g]);
    }
  }

  // ---- states ----
  float hi_[4], ci_[4], hg_[4], cg_[4], u_[4];
  #pragma unroll
  for (int r = 0; r < 4; ++r) {
    size_t gi = (size_t)(bbase + r0 + r) * 64 + col;
    hi_[r] = hi0[gi]; ci_[r] = ci0[gi];
    hg_[r] = hg0[gi]; cg_[r] = cg0[gi];
    u_[r]  = ug0[gi];
  }
  const float bprm = BPR[col], bprv = BPR[64 + col];
  const float bpom = BPO[col], bpov = BPO[64 + col];
  const float bd   = BD[col];

  #pragma unroll
  for (int r = 0; r < 4; ++r) {
    WR_FR(0, r0 + r, col, hi_[r]);   // hi -> H0
    WR_FR(2, r0 + r, col, hg_[r]);
    WR_FR(4, r0 + r, col, u_[r]);    // u -> U0
  }
  __syncthreads();   // As reads done + fr visible; wgL may now be overwritten

  // ---- stage WI/WG B-frags into LDS (64 KB each from L2) ----
  {
    const uint4* srcI = (const uint4*)(FB + FR_WI);
    uint4* dI = (uint4*)wiL;
    for (int i = tid; i < 4096; i += 512) dI[i] = srcI[i];
    const uint4* srcG = (const uint4*)(FB + FR_WG);
    uint4* dG = (uint4*)wgL;
    for (int i = tid; i < 4096; i += 512) dG[i] = srcG[i];
  }
  __syncthreads();

  const float zo = s ? 0.2f : 0.3f, zo1 = 1.0f - zo;

  // ---- hoisted output pointers & eps stream ----
  const unsigned gi0 = (unsigned)((bbase + r0) * 64 + col);
  float* o_prm = out + (size_t)(2 + (2 * s) * nd) * BN + gi0;
  float* o_prv = out + (size_t)(2 + (2 * s + 1) * nd) * BN + gi0;
  float* o_pom = out + (size_t)(2 + (4 + 2 * s) * nd) * BN + gi0;
  float* o_pov = out + (size_t)(2 + (5 + 2 * s) * nd) * BN + gi0;
  unsigned e0 = gi0;
  const unsigned BNu = (unsigned)BN;
  const unsigned eseed = 1u + (unsigned)s;
  const float* ep = USE_EPS ? (eps_buf + (size_t)s * ndBN + gi0) : (const float*)0;

  for (int t = 0; t < nd; ++t) {
    const int cb = t & 1;
    // ---- eps prefetch (used in P3) ----
    float epre[4];
    if (USE_EPS) {
      #pragma unroll
      for (int r = 0; r < 4; ++r) epre[r] = ep[r * 64];
    }
    // ---- P1: A-frags of hg_old, hi_old ----
    bf16x8 a_hg0 = LD_FR(2, 0), a_hg1 = LD_FR(2, 1);
    bf16x8 a_hi0 = LD_FR(cb, 0), a_hi1 = LD_FR(cb, 1);

    // ---- P2: prior head (regs) + inference LSTM (LDS weights) ----
    {
      f32x4 am = {bprm, bprm, bprm, bprm};
      f32x4 av = {bprv, bprv, bprv, bprv};
      am = MFMA(a_hg0, wpr[0][0], am);
      am = MFMA(a_hg1, wpr[1][0], am);
      av = MFMA(a_hg0, wpr[0][1], av);
      av = MFMA(a_hg1, wpr[1][1], av);
      #pragma unroll
      for (int r = 0; r < 4; ++r) {
        o_prm[r * 64] = am[r];
        o_prv[r * 64] = av[r];
      }
    }
    {
      f32x4 acc[4];
      #pragma unroll
      for (int g = 0; g < 4; ++g) acc[g] = preI[g];
      #pragma unroll
      for (int g = 0; g < 4; ++g) {
        acc[g] = MFMA(a_hg0, LD_WI(0, g * 4 + ws), acc[g]);
        acc[g] = MFMA(a_hg1, LD_WI(1, g * 4 + ws), acc[g]);
        acc[g] = MFMA(a_hi0, LD_WI(2, g * 4 + ws), acc[g]);
        acc[g] = MFMA(a_hi1, LD_WI(3, g * 4 + ws), acc[g]);
      }
      #pragma unroll
      for (int r = 0; r < 4; ++r) {
        float ig = sigf(acc[0][r]), fg = sigf(acc[1][r]);
        float gg = tanh_f(acc[2][r]), og = sigf(acc[3][r]);
        float cn = fmaf(fg, ci_[r], ig * gg);
        float hn = og * tanh_f(cn);
        hi_[r] = fmaf(zo, hi_[r], zo1 * hn);
        ci_[r] = fmaf(zo, ci_[r], zo1 * cn);
        WR_FR(cb ^ 1, r0 + r, col, hi_[r]);   // new hi -> other buffer
      }
    }
    __syncthreads();                                 // B2 (hi ready)

    // ---- P3: posterior head (regs) + z sample ----
    {
      bf16x8 a0 = LD_FR(cb ^ 1, 0), a1 = LD_FR(cb ^ 1, 1);
      f32x4 am = {bpom, bpom, bpom, bpom};
      f32x4 av = {bpov, bpov, bpov, bpov};
      am = MFMA(a0, wpo[0][0], am);
      am = MFMA(a1, wpo[1][0], am);
      av = MFMA(a0, wpo[0][1], av);
      av = MFMA(a1, wpo[1][1], av);
      #pragma unroll
      for (int r = 0; r < 4; ++r) {
        o_pom[r * 64] = am[r];
        o_pov[r * 64] = av[r];
        float e = USE_EPS ? epre[r] : eps_threefry(eseed, e0 + r * 64);
        float z = fmaf(__expf(0.5f * av[r]), e, am[r]);
        WR_FR(3, r0 + r, col, z);
      }
    }
    __syncthreads();                                 // B3 (z ready)

    // ---- P4: generator LSTM (LDS weights; x1 = z, x2 = hg_old) ----
    {
      bf16x8 az0 = LD_FR(3, 0), az1 = LD_FR(3, 1);
      f32x4 acc[4];
      #pragma unroll
      for (int g = 0; g < 4; ++g) acc[g] = preG[g];
      #pragma unroll
      for (int g = 0; g < 4; ++g) {
        acc[g] = MFMA(az0,   LD_WG(0, g * 4 + ws), acc[g]);
        acc[g] = MFMA(az1,   LD_WG(1, g * 4 + ws), acc[g]);
        acc[g] = MFMA(a_hg0, LD_WG(2, g * 4 + ws), acc[g]);
        acc[g] = MFMA(a_hg1, LD_WG(3, g * 4 + ws), acc[g]);
      }
      #pragma unroll
      for (int r = 0; r < 4; ++r) {
        float ig = sigf(acc[0][r]), fg = sigf(acc[1][r]);
        float gg = tanh_f(acc[2][r]), og = sigf(acc[3][r]);
        float cn = fmaf(fg, cg_[r], ig * gg);
        float hn = og * tanh_f(cn);
        hg_[r] = fmaf(zo, hg_[r], zo1 * hn);
        cg_[r] = fmaf(zo, cg_[r], zo1 * cn);
        WR_FR(2, r0 + r, col, hg_[r]);
      }
    }
    __syncthreads();                                 // B4 (hg ready)

    // ---- P5: canvas delta (WD in regs); no trailing barrier needed:
    //      writes only u dbuf, whose next reader (P5 of t+1) is behind
    //      B2/B3/B4 of t+1; next-step P1/P2 touch disjoint fr buffers. ----
    {
      bf16x8 au0 = LD_FR(4 + cb, 0), au1 = LD_FR(4 + cb, 1);
      bf16x8 ah0 = LD_FR(2, 0), ah1 = LD_FR(2, 1);
      f32x4 acc = {bd, bd, bd, bd};
      acc = MFMA(au0, wd[0], acc);
      acc = MFMA(au1, wd[1], acc);
      acc = MFMA(ah0, wd[2], acc);
      acc = MFMA(ah1, wd[3], acc);
      #pragma unroll
      for (int r = 0; r < 4; ++r) {
        float a = acc[r];
        float d = a > 0.0f ? a : 0.01f * a;
        u_[r] += d;
        WR_FR(4 + (cb ^ 1), r0 + r, col, u_[r]);   // new u -> other buffer
      }
    }

    o_prm += BN; o_prv += BN; o_pom += BN; o_pov += BN;
    e0 += BNu;
    if (USE_EPS) ep += BN;
  }

  // ---- final canvases ----
  #pragma unroll
  for (int r = 0; r < 4; ++r) {
    size_t gi = (size_t)(bbase + r0 + r) * 64 + col;
    out[(size_t)s * BN + gi] = u_[r];
  }
}

extern "C" void kernel_launch(void* const* d_in, const int* in_sizes, int n_in,
                              void* d_out, int out_size, void* d_ws, size_t ws_size,
                              hipStream_t stream)
{
  const float* cnd = (const float*)d_in[1];
  const float* qj  = (const float*)d_in[2];
  const float* qd  = (const float*)d_in[3];
  const float* qv  = (const float*)d_in[4];
  const float* hi_j0 = (const float*)d_in[5];
  const float* ci_j0 = (const float*)d_in[6];
  const float* hi_d0 = (const float*)d_in[8];
  const float* ci_d0 = (const float*)d_in[9];
  const float* hg_j0 = (const float*)d_in[11];
  const float* cg_j0 = (const float*)d_in[12];
  const float* hg_d0 = (const float*)d_in[14];
  const float* cg_d0 = (const float*)d_in[15];
  const float* ug_j0 = (const float*)d_in[17];
  const float* ug_d0 = (const float*)d_in[18];
  const float* Wij = (const float*)d_in[19]; const float* bij = (const float*)d_in[20];
  const float* Wid = (const float*)d_in[21]; const float* bid = (const float*)d_in[22];
  const float* Wgj = (const float*)d_in[23]; const float* bgj = (const float*)d_in[24];
  const float* Wgd = (const float*)d_in[25]; const float* bgd = (const float*)d_in[26];
  const float* Wpoj = (const float*)d_in[27]; const float* bpoj = (const float*)d_in[28];
  const float* Wpod = (const float*)d_in[29]; const float* bpod = (const float*)d_in[30];
  const float* Wprj = (const float*)d_in[31]; const float* bprj = (const float*)d_in[32];
  const float* Wprd = (const float*)d_in[33]; const float* bprd = (const float*)d_in[34];
  const float* Wdj = (const float*)d_in[35]; const float* bdj = (const float*)d_in[36];
  const float* Wdd = (const float*)d_in[37]; const float* bdd = (const float*)d_in[38];

  const int B = in_sizes[1] / 256;                 // cnd_repr is [B,256]
  const int slots = out_size / (B * 64);           // 2 + 8*ndraw
  const int nd = (slots - 2) / 8;

  // ws layout: frB (2*FR_SIDE u16) | sBs (592*512 u16) | eps (2*nd*B*64 f32)
  unsigned short* frB = (unsigned short*)d_ws;
  unsigned short* sBs = frB + 2 * FR_SIDE;
  size_t epsOff = (size_t)2 * FR_SIDE * 2 + (size_t)592 * 512 * 2;
  epsOff = (epsOff + 255) & ~(size_t)255;
  const unsigned ndBN = (unsigned)((size_t)nd * B * 64);
  float* epsBuf = (float*)((char*)d_ws + epsOff);
  const bool useEps = ws_size >= epsOff + (size_t)2 * ndBN * 4;
  float* out = (float*)d_out;

  const int epsBlocks = useEps ? (int)((2u * ndBN + 2047u) / 2048u) : 0;
  GeRN_prepEps<<<236 + epsBlocks, 256, 0, stream>>>(
      Wij, Wid, Wgj, Wgd, Wprj, Wprd, Wpoj, Wpod, Wdj, Wdd, frB, sBs,
      epsBuf, ndBN);
  if (useEps) {
    GeRN_recur<1><<<2 * (B / 32), 512, 0, stream>>>(
        frB, sBs, cnd, qj, qd, qv, bij, bid, bgj, bgd,
        bprj, bprd, bpoj, bpod, bdj, bdd,
        hi_j0, ci_j0, hi_d0, ci_d0, hg_j0, cg_j0, hg_d0, cg_d0, ug_j0, ug_d0,
        epsBuf, ndBN, out, B, nd);
  } else {
    GeRN_recur<0><<<2 * (B / 32), 512, 0, stream>>>(
        frB, sBs, cnd, qj, qd, qv, bij, bid, bgj, bgd,
        bprj, bprd, bpoj, bpod, bdj, bdd,
        hi_j0, ci_j0, hi_d0, ci_d0, hg_j0, cg_j0, hg_d0, cg_d0, ug_j0, ug_d0,
        (const float*)0, ndBN, out, B, nd);
  }
}